// Round 2
// baseline (267.220 us; speedup 1.0000x reference)
//
#include <hip/hip_runtime.h>
#include <math.h>

#define ROWN 10000
#define COLN 4096
#define DIM 16
#define EN 1000000
#define BIGF 100000.0f

// per-column record: 48 float4 (768 B)
//  [0]        = (1, t, t^2/2, t^3/6)
//  [1..40]    = L^T ragged quads: for k=0..15, quads q=k/4..3, elem j = L[4q+j][k]
//  [41..44]   = z_cols[c] (16 floats)
//  [45]       = (gamma_col, 0, 0, 0)
#define RECQ 48
#define RECF (RECQ * 4)

#define NBH 64       // histogram chunks (run inside init alongside col blocks)
#define CHH 15625    // EN / NBH exact
#define NBS 250      // scatter chunks
#define CHS 4000     // EN / NBS exact

struct Ctrl { int done; int pad; double acc; };

// ragged L^T quad tables
__constant__ int QK[40] = {0,0,0,0, 1,1,1,1, 2,2,2,2, 3,3,3,3,
                           4,4,4, 5,5,5, 6,6,6, 7,7,7,
                           8,8, 9,9, 10,10, 11,11, 12, 13, 14, 15};
__constant__ int QQ[40] = {0,1,2,3, 0,1,2,3, 0,1,2,3, 0,1,2,3,
                           1,2,3, 1,2,3, 1,2,3, 1,2,3,
                           2,3, 2,3, 2,3, 2,3, 3, 3, 3, 3};

// offset of k's first quad within the ragged block (compile-time foldable)
__host__ __device__ __forceinline__ constexpr int offk(int k) {
    return (k < 4) ? k * 4
         : (k < 8) ? 16 + (k - 4) * 3
         : (k < 12) ? 28 + (k - 8) * 2
         : 36 + (k - 12);
}

// ---------- fused init: per-column record build + chunk histogram ----------
// gcnt must be zeroed before this kernel.
__global__ __launch_bounds__(256) void init2(
    const float* __restrict__ z_cols, const float* __restrict__ gamma_cols,
    const float* __restrict__ L, const float* __restrict__ col_times,
    const int* __restrict__ col_idx_list, float* __restrict__ rec,
    const int* __restrict__ mc, int* __restrict__ gcnt)
{
    const int tid = threadIdx.x;
    if (blockIdx.x < COLN) {
        __shared__ float Lsh[DIM][DIM + 1];
        const int c = blockIdx.x;
        const int cidx = col_idx_list[c];
        Lsh[tid >> 4][tid & 15] = L[(size_t)cidx * 256 + tid];
        __syncthreads();

        float4* r = (float4*)(rec + (size_t)c * RECF);
        if (tid < 40) {
            const int k = QK[tid];
            const int d = 4 * QQ[tid];
            r[1 + tid] = make_float4(Lsh[d][k], Lsh[d+1][k], Lsh[d+2][k], Lsh[d+3][k]);
        } else if (tid < 44) {
            const int j = tid - 40;
            const float* zp = z_cols + (size_t)c * DIM + 4 * j;
            r[41 + j] = make_float4(zp[0], zp[1], zp[2], zp[3]);
        } else if (tid == 44) {
            const float t = col_times[c];
            r[0]  = make_float4(1.0f, t, 0.5f * t * t, t * t * t * (1.0f / 6.0f));
            r[45] = make_float4(gamma_cols[c], 0.0f, 0.0f, 0.0f);
        }
    } else {
        __shared__ int h[COLN];
        const int b = blockIdx.x - COLN;
        for (int i = tid; i < COLN; i += 256) h[i] = 0;
        __syncthreads();
        const int lo = b * CHH, hi = min(lo + CHH, EN);
        for (int e = lo + tid; e < hi; e += 256)
            atomicAdd(&h[mc[e]], 1);
        __syncthreads();
        for (int i = tid; i < COLN; i += 256) {
            int v = h[i];
            if (v) atomicAdd(&gcnt[i], v);
        }
    }
}

// ---------- scatter with fused redundant scan -------------------------------
// Every block scans gcnt in LDS (cheap, parallel); block 0 publishes gbase
// for the edge kernel. Removes the serial single-block scan dispatch.
__global__ __launch_bounds__(512) void scatter3(
    const int* __restrict__ mr, const int* __restrict__ mc,
    const int* __restrict__ yy, const int* __restrict__ gcnt,
    int* __restrict__ gcur, int* __restrict__ gbase,
    int* __restrict__ packed)
{
    __shared__ int bases[COLN];
    __shared__ int lh[COLN];
    __shared__ int sums[512];
    const int tid = threadIdx.x;

    // --- tight exclusive scan of the 4096 counts ---
    int s = 0;
    #pragma unroll
    for (int i = 0; i < 8; ++i) {
        int c = tid * 8 + i;
        int v = gcnt[c];
        bases[c] = v;                 // temp: counts
        s += v;
    }
    sums[tid] = s;
    __syncthreads();
    for (int off = 1; off < 512; off <<= 1) {
        int v = (tid >= off) ? sums[tid - off] : 0;
        __syncthreads();
        sums[tid] += v;
        __syncthreads();
    }
    int run = (tid == 0) ? 0 : sums[tid - 1];
    #pragma unroll
    for (int i = 0; i < 8; ++i) {
        int c = tid * 8 + i;
        int v = bases[c];
        bases[c] = run;               // now: exclusive base
        run += v;
    }
    if (blockIdx.x == 0) {            // publish for edge kernel (own 8, no sync needed)
        #pragma unroll
        for (int i = 0; i < 8; ++i) { int c = tid * 8 + i; gbase[c] = bases[c]; }
    }

    // --- per-chunk local histogram ---
    for (int i = tid; i < COLN; i += 512) lh[i] = 0;
    __syncthreads();
    const int b = blockIdx.x;
    const int lo = b * CHS, hi = min(lo + CHS, EN);
    for (int e = lo + tid; e < hi; e += 512)
        atomicAdd(&lh[mc[e]], 1);
    __syncthreads();

    // --- reserve global ranges (gcur is offset-from-base, zeroed) ---
    for (int i = tid; i < COLN; i += 512) {
        int cntl = lh[i];
        if (cntl) lh[i] = bases[i] + atomicAdd(&gcur[i], cntl);
    }
    __syncthreads();

    // --- place ---
    for (int e = lo + tid; e < hi; e += 512) {
        int c = mc[e];
        int pos = atomicAdd(&lh[c], 1);
        packed[pos] = mr[e] | (yy[e] << 14);      // 14 bits row + 3 bits y
    }
}

// log( Phi(hi) - Phi(lo) ), cancellation-free, branch-light, always finite.
__device__ __forceinline__ float log_cdf_diff_f(float hi, float lo) {
    const float r = 0.70710678118654752440f;
    if (hi + lo < 0.0f) { float t = hi; hi = -lo; lo = -t; }
    float d = erfcf(lo * r) - erfcf(hi * r);
    return logf(0.5f * fmaxf(d, 1e-37f));
}

// ---------- per-column edge kernel: all gathers issued before use ----------
__global__ __launch_bounds__(256) void edge3(
    const float* __restrict__ z_rows, const float* __restrict__ gamma_rows,
    const float4* __restrict__ rec4, const float* __restrict__ b,
    const float* __restrict__ sigma, const int* __restrict__ packed,
    const int* __restrict__ gbase, const int* __restrict__ gcnt,
    Ctrl* __restrict__ ctrl, float* __restrict__ out)
{
    __shared__ float4 R[RECQ];
    __shared__ float th[6];
    __shared__ double wsum[4];
    const int c = blockIdx.x;
    const int tid = threadIdx.x;
    if (tid < RECQ) R[tid] = rec4[(size_t)c * RECQ + tid];
    if (tid == 0) { th[0] = -BIGF; th[5] = BIGF; }
    if (tid < 4)  th[1 + tid] = b[tid];
    __syncthreads();

    const float inv_s = 1.0f / sigma[0];
    const int base = gbase[c];
    const int cnt  = gcnt[c];
    const float4 t0 = R[0];
    const float tp1 = t0.y, tp2 = t0.z, tp3 = t0.w;
    const float4 zc0 = R[41], zc1 = R[42], zc2 = R[43], zc3 = R[44];
    const float gcol = R[45].x;
    const size_t SL = (size_t)ROWN * DIM;

    double acc = 0.0;
    for (int i = tid; i < cnt; i += 256) {
        const int p   = packed[base + i];
        const int row = p & 0x3FFF;
        const int yv  = (p >> 14) & 7;
        const float* zr = z_rows + (size_t)row * DIM;

        // issue ALL 16 gather loads (4 planes x 4 quads) before any use:
        // one latency wait per edge instead of four serialized ones.
        float4 a[16];
        #pragma unroll
        for (int v = 0; v < 4; ++v) {
            #pragma unroll
            for (int q = 0; q < 4; ++q)
                a[v * 4 + q] = *(const float4*)(zr + (size_t)v * SL + q * 4);
        }
        const float ga = gamma_rows[row];

        // delta[d] = sum_v z_rows[v,row,d]*tp[v] - zc[d]
        float d_[DIM];
        #pragma unroll
        for (int q = 0; q < 4; ++q) {
            const float4 zc = (q == 0) ? zc0 : (q == 1) ? zc1 : (q == 2) ? zc2 : zc3;
            d_[4*q+0] = fmaf(a[12+q].x, tp3, fmaf(a[8+q].x, tp2, fmaf(a[4+q].x, tp1, a[q].x))) - zc.x;
            d_[4*q+1] = fmaf(a[12+q].y, tp3, fmaf(a[8+q].y, tp2, fmaf(a[4+q].y, tp1, a[q].y))) - zc.y;
            d_[4*q+2] = fmaf(a[12+q].z, tp3, fmaf(a[8+q].z, tp2, fmaf(a[4+q].z, tp1, a[q].z))) - zc.z;
            d_[4*q+3] = fmaf(a[12+q].w, tp3, fmaf(a[8+q].w, tp2, fmaf(a[4+q].w, tp1, a[q].w))) - zc.w;
        }

        // nsq = || delta^T L ||^2, ragged lower-triangular at quad granularity
        float nsq = 0.0f;
        #pragma unroll
        for (int k = 0; k < DIM; ++k) {
            const int q0 = k >> 2;
            float t = 0.0f;
            #pragma unroll
            for (int q = q0; q < 4; ++q) {
                const float4 lv = R[1 + offk(k) + (q - q0)];
                t = fmaf(lv.x, d_[4*q+0],
                    fmaf(lv.y, d_[4*q+1],
                    fmaf(lv.z, d_[4*q+2],
                    fmaf(lv.w, d_[4*q+3], t))));
            }
            nsq = fmaf(t, t, nsq);
        }

        const float f = ga + gcol - sqrtf(nsq);
        acc += (double)log_cdf_diff_f((th[yv] - f) * inv_s,
                                      (th[yv - 1] - f) * inv_s);
    }

    #pragma unroll
    for (int off = 32; off > 0; off >>= 1) acc += __shfl_down(acc, off, 64);
    const int lane = tid & 63;
    const int wid  = tid >> 6;
    if (lane == 0) wsum[wid] = acc;
    __syncthreads();
    if (tid == 0) {
        atomicAdd(&ctrl->acc, wsum[0] + wsum[1] + wsum[2] + wsum[3]);
        __threadfence();
        const int old = atomicAdd(&ctrl->done, 1);   // arrival counter
        if (old == COLN - 1) {
            __threadfence();
            out[0] = -(float)atomicAdd(&ctrl->acc, 0.0);  // read full sum
        }
    }
}

extern "C" void kernel_launch(void* const* d_in, const int* in_sizes, int n_in,
                              void* d_out, int out_size, void* d_ws, size_t ws_size,
                              hipStream_t stream) {
    const float* z_rows       = (const float*)d_in[0];
    const float* z_cols       = (const float*)d_in[1];
    const float* gamma_rows   = (const float*)d_in[2];
    const float* gamma_cols   = (const float*)d_in[3];
    const float* L            = (const float*)d_in[4];
    const float* b            = (const float*)d_in[5];
    const float* sigma        = (const float*)d_in[6];
    const float* col_times    = (const float*)d_in[7];
    const int*   mat_rows     = (const int*)d_in[8];
    const int*   mat_cols     = (const int*)d_in[9];
    const int*   y            = (const int*)d_in[10];
    const int*   col_idx_list = (const int*)d_in[11];

    // workspace layout (16B aligned):
    //   rec   : 4096*192*4 = 3,145,728 B
    //   gcnt  : 16,384 B
    //   gbase : 16,384 B
    //   gcur  : 16,384 B
    //   ctrl  : 128 B
    //   pk    : EN*4 = 4,000,000 B
    char* ws = (char*)d_ws;
    float* rec   = (float*)ws;
    int*   gcnt  = (int*)(ws + 3145728);
    int*   gbase = (int*)(ws + 3162112);
    int*   gcur  = (int*)(ws + 3178496);
    Ctrl*  ctrl  = (Ctrl*)(ws + 3194880);
    int*   pk    = (int*)(ws + 3195008);

    hipMemsetAsync(gcnt, 0, 3 * 16384 + 128, stream);   // counts+bases+cursors+ctrl
    init2<<<COLN + NBH, 256, 0, stream>>>(
        z_cols, gamma_cols, L, col_times, col_idx_list, rec, mat_cols, gcnt);
    scatter3<<<NBS, 512, 0, stream>>>(mat_rows, mat_cols, y, gcnt, gcur, gbase, pk);
    edge3<<<COLN, 256, 0, stream>>>(z_rows, gamma_rows, (const float4*)rec,
                                    b, sigma, pk, gbase, gcnt, ctrl, (float*)d_out);
}

// Round 3
// 171.365 us; speedup vs baseline: 1.5594x; 1.5594x over previous
//
#include <hip/hip_runtime.h>
#include <math.h>

#define ROWN 10000
#define COLN 4096
#define DIM 16
#define EN 1000000
#define BIGF 100000.0f

// per-column record: 48 float4 (768 B)
//  [0]        = (1, t, t^2/2, t^3/6)
//  [1..40]    = L^T ragged quads: for k=0..15, quads q=k/4..3, elem j = L[4q+j][k]
//  [41..44]   = z_cols[c] (16 floats)
//  [45]       = (gamma_col, 0, 0, 0)
#define RECQ 48
#define RECF (RECQ * 4)

#define NBT 40       // z-transpose blocks (250 rows each)
#define RPT 250      // rows per transpose block
#define NBH 64       // histogram chunks
#define CHH 15625    // EN / NBH exact
#define NBS 250      // scatter chunks
#define CHS 4000     // EN / NBS exact

// ragged L^T quad tables
__constant__ int QK[40] = {0,0,0,0, 1,1,1,1, 2,2,2,2, 3,3,3,3,
                           4,4,4, 5,5,5, 6,6,6, 7,7,7,
                           8,8, 9,9, 10,10, 11,11, 12, 13, 14, 15};
__constant__ int QQ[40] = {0,1,2,3, 0,1,2,3, 0,1,2,3, 0,1,2,3,
                           1,2,3, 1,2,3, 1,2,3, 1,2,3,
                           2,3, 2,3, 2,3, 2,3, 3, 3, 3, 3};

// offset of k's first quad within the ragged block (compile-time foldable)
__host__ __device__ __forceinline__ constexpr int offk(int k) {
    return (k < 4) ? k * 4
         : (k < 8) ? 16 + (k - 4) * 3
         : (k < 12) ? 28 + (k - 8) * 2
         : 36 + (k - 12);
}

// ---------- fused init: z-transpose + chunk histogram + column records -----
// gcnt must be zeroed before this kernel.
__global__ __launch_bounds__(256) void init3(
    const float* __restrict__ z_rows, const float* __restrict__ z_cols,
    const float* __restrict__ gamma_cols, const float* __restrict__ L,
    const float* __restrict__ col_times, const int* __restrict__ col_idx_list,
    float* __restrict__ rec, float* __restrict__ zt,
    const int* __restrict__ mc, int* __restrict__ gcnt)
{
    const int tid = threadIdx.x;
    if (blockIdx.x < NBT) {
        // ---- transpose z_rows [4][ROW][16] -> zt [ROW][4][16] ----
        const int r0 = blockIdx.x * RPT;
        const size_t SL = (size_t)ROWN * DIM;
        float4* dst = (float4*)zt;                       // row stride 16 quads
        #pragma unroll
        for (int v = 0; v < 4; ++v) {
            const float4* src = (const float4*)(z_rows + (size_t)v * SL
                                                + (size_t)r0 * DIM);
            for (int idx = tid; idx < RPT * 4; idx += 256) {
                const int r = idx >> 2, q = idx & 3;
                dst[(size_t)(r0 + r) * 16 + v * 4 + q] = src[idx];
            }
        }
    } else if (blockIdx.x < NBT + NBH) {
        // ---- per-chunk histogram of mat_cols ----
        __shared__ int h[COLN];
        const int b = blockIdx.x - NBT;
        for (int i = tid; i < COLN; i += 256) h[i] = 0;
        __syncthreads();
        const int lo = b * CHH, hi = min(lo + CHH, EN);
        for (int e = lo + tid; e < hi; e += 256)
            atomicAdd(&h[mc[e]], 1);
        __syncthreads();
        for (int i = tid; i < COLN; i += 256) {
            int v = h[i];
            if (v) atomicAdd(&gcnt[i], v);
        }
    } else {
        // ---- per-column record ----
        __shared__ float Lsh[DIM][DIM + 1];
        const int c = blockIdx.x - (NBT + NBH);
        const int cidx = col_idx_list[c];
        Lsh[tid >> 4][tid & 15] = L[(size_t)cidx * 256 + tid];
        __syncthreads();

        float4* r = (float4*)(rec + (size_t)c * RECF);
        if (tid < 40) {
            const int k = QK[tid];
            const int d = 4 * QQ[tid];
            r[1 + tid] = make_float4(Lsh[d][k], Lsh[d+1][k], Lsh[d+2][k], Lsh[d+3][k]);
        } else if (tid < 44) {
            const int j = tid - 40;
            const float* zp = z_cols + (size_t)c * DIM + 4 * j;
            r[41 + j] = make_float4(zp[0], zp[1], zp[2], zp[3]);
        } else if (tid == 44) {
            const float t = col_times[c];
            r[0]  = make_float4(1.0f, t, 0.5f * t * t, t * t * t * (1.0f / 6.0f));
            r[45] = make_float4(gamma_cols[c], 0.0f, 0.0f, 0.0f);
        }
    }
}

// ---------- scatter with fused redundant scan -------------------------------
__global__ __launch_bounds__(512) void scatter3(
    const int* __restrict__ mr, const int* __restrict__ mc,
    const int* __restrict__ yy, const int* __restrict__ gcnt,
    int* __restrict__ gcur, int* __restrict__ gbase,
    int* __restrict__ packed)
{
    __shared__ int bases[COLN];
    __shared__ int lh[COLN];
    __shared__ int sums[512];
    const int tid = threadIdx.x;

    // tight exclusive scan of the 4096 counts (redundant per block, cheap)
    int s = 0;
    #pragma unroll
    for (int i = 0; i < 8; ++i) {
        int c = tid * 8 + i;
        int v = gcnt[c];
        bases[c] = v;
        s += v;
    }
    sums[tid] = s;
    __syncthreads();
    for (int off = 1; off < 512; off <<= 1) {
        int v = (tid >= off) ? sums[tid - off] : 0;
        __syncthreads();
        sums[tid] += v;
        __syncthreads();
    }
    int run = (tid == 0) ? 0 : sums[tid - 1];
    #pragma unroll
    for (int i = 0; i < 8; ++i) {
        int c = tid * 8 + i;
        int v = bases[c];
        bases[c] = run;
        run += v;
    }
    if (blockIdx.x == 0) {
        #pragma unroll
        for (int i = 0; i < 8; ++i) { int c = tid * 8 + i; gbase[c] = bases[c]; }
    }

    // per-chunk local histogram
    for (int i = tid; i < COLN; i += 512) lh[i] = 0;
    __syncthreads();
    const int b = blockIdx.x;
    const int lo = b * CHS, hi = min(lo + CHS, EN);
    for (int e = lo + tid; e < hi; e += 512)
        atomicAdd(&lh[mc[e]], 1);
    __syncthreads();

    // reserve global ranges (gcur = offset-from-base, zeroed)
    for (int i = tid; i < COLN; i += 512) {
        int cntl = lh[i];
        if (cntl) lh[i] = bases[i] + atomicAdd(&gcur[i], cntl);
    }
    __syncthreads();

    // place
    for (int e = lo + tid; e < hi; e += 512) {
        int c = mc[e];
        int pos = atomicAdd(&lh[c], 1);
        packed[pos] = mr[e] | (yy[e] << 14);      // 14 bits row + 3 bits y
    }
}

// log( Phi(hi) - Phi(lo) ), cancellation-free, branch-light, always finite.
__device__ __forceinline__ float log_cdf_diff_f(float hi, float lo) {
    const float r = 0.70710678118654752440f;
    if (hi + lo < 0.0f) { float t = hi; hi = -lo; lo = -t; }
    float d = erfcf(lo * r) - erfcf(hi * r);
    return logf(0.5f * fmaxf(d, 1e-37f));
}

// ---------- per-column edge kernel: contiguous z record, no atomics --------
__global__ __launch_bounds__(128) void edge4(
    const float* __restrict__ zt, const float* __restrict__ gamma_rows,
    const float4* __restrict__ rec4, const float* __restrict__ b,
    const float* __restrict__ sigma, const int* __restrict__ packed,
    const int* __restrict__ gbase, const int* __restrict__ gcnt,
    double* __restrict__ bsum)
{
    __shared__ float4 R[RECQ];
    __shared__ float th[6];
    __shared__ double wsum[2];
    const int c = blockIdx.x;
    const int tid = threadIdx.x;
    if (tid < RECQ) R[tid] = rec4[(size_t)c * RECQ + tid];
    if (tid == 0) { th[0] = -BIGF; th[5] = BIGF; }
    if (tid < 4)  th[1 + tid] = b[tid];
    __syncthreads();

    const float inv_s = 1.0f / sigma[0];
    const int base = gbase[c];
    const int cnt  = gcnt[c];
    const float4 t0 = R[0];
    const float tp1 = t0.y, tp2 = t0.z, tp3 = t0.w;
    const float4 zc0 = R[41], zc1 = R[42], zc2 = R[43], zc3 = R[44];
    const float gcol = R[45].x;

    double acc = 0.0;
    for (int i = tid; i < cnt; i += 128) {
        const int p   = packed[base + i];
        const int row = p & 0x3FFF;
        const int yv  = (p >> 14) & 7;
        const float4* zp = (const float4*)(zt + (size_t)row * 64);

        // ALL 16 loads from ONE 256B contiguous region (2 cache lines),
        // issued before any use: one latency wait per edge.
        float4 a[16];
        #pragma unroll
        for (int j = 0; j < 16; ++j) a[j] = zp[j];
        const float ga = gamma_rows[row];

        // delta[d] = sum_v a[v*4+q]*tp[v] - zc[d]
        float d_[DIM];
        #pragma unroll
        for (int q = 0; q < 4; ++q) {
            const float4 zc = (q == 0) ? zc0 : (q == 1) ? zc1 : (q == 2) ? zc2 : zc3;
            d_[4*q+0] = fmaf(a[12+q].x, tp3, fmaf(a[8+q].x, tp2, fmaf(a[4+q].x, tp1, a[q].x))) - zc.x;
            d_[4*q+1] = fmaf(a[12+q].y, tp3, fmaf(a[8+q].y, tp2, fmaf(a[4+q].y, tp1, a[q].y))) - zc.y;
            d_[4*q+2] = fmaf(a[12+q].z, tp3, fmaf(a[8+q].z, tp2, fmaf(a[4+q].z, tp1, a[q].z))) - zc.z;
            d_[4*q+3] = fmaf(a[12+q].w, tp3, fmaf(a[8+q].w, tp2, fmaf(a[4+q].w, tp1, a[q].w))) - zc.w;
        }

        // nsq = || delta^T L ||^2, ragged lower-triangular at quad granularity
        float nsq = 0.0f;
        #pragma unroll
        for (int k = 0; k < DIM; ++k) {
            const int q0 = k >> 2;
            float t = 0.0f;
            #pragma unroll
            for (int q = q0; q < 4; ++q) {
                const float4 lv = R[1 + offk(k) + (q - q0)];
                t = fmaf(lv.x, d_[4*q+0],
                    fmaf(lv.y, d_[4*q+1],
                    fmaf(lv.z, d_[4*q+2],
                    fmaf(lv.w, d_[4*q+3], t))));
            }
            nsq = fmaf(t, t, nsq);
        }

        const float f = ga + gcol - sqrtf(nsq);
        acc += (double)log_cdf_diff_f((th[yv] - f) * inv_s,
                                      (th[yv - 1] - f) * inv_s);
    }

    #pragma unroll
    for (int off = 32; off > 0; off >>= 1) acc += __shfl_down(acc, off, 64);
    const int lane = tid & 63;
    const int wid  = tid >> 6;
    if (lane == 0) wsum[wid] = acc;
    __syncthreads();
    if (tid == 0) bsum[c] = wsum[0] + wsum[1];   // plain store, zero contention
}

// ---------- final reduction of 4096 per-block partials ---------------------
__global__ __launch_bounds__(512) void finalize2(const double* __restrict__ bsum,
                                                 float* __restrict__ out)
{
    __shared__ double s[512];
    const int tid = threadIdx.x;
    double a = 0.0;
    #pragma unroll
    for (int i = 0; i < 8; ++i) a += bsum[tid * 8 + i];
    s[tid] = a;
    __syncthreads();
    for (int off = 256; off > 0; off >>= 1) {
        if (tid < off) s[tid] += s[tid + off];
        __syncthreads();
    }
    if (tid == 0) out[0] = -(float)s[0];
}

extern "C" void kernel_launch(void* const* d_in, const int* in_sizes, int n_in,
                              void* d_out, int out_size, void* d_ws, size_t ws_size,
                              hipStream_t stream) {
    const float* z_rows       = (const float*)d_in[0];
    const float* z_cols       = (const float*)d_in[1];
    const float* gamma_rows   = (const float*)d_in[2];
    const float* gamma_cols   = (const float*)d_in[3];
    const float* L            = (const float*)d_in[4];
    const float* b            = (const float*)d_in[5];
    const float* sigma        = (const float*)d_in[6];
    const float* col_times    = (const float*)d_in[7];
    const int*   mat_rows     = (const int*)d_in[8];
    const int*   mat_cols     = (const int*)d_in[9];
    const int*   y            = (const int*)d_in[10];
    const int*   col_idx_list = (const int*)d_in[11];

    // workspace layout (16B aligned):
    //   rec   : 3,145,728 B   @ 0
    //   zt    : 2,560,000 B   @ 3,145,728
    //   gcnt  : 16,384 B      @ 5,705,728
    //   gbase : 16,384 B      @ 5,722,112
    //   gcur  : 16,384 B      @ 5,738,496
    //   bsum  : 32,768 B      @ 5,754,880
    //   pk    : 4,000,000 B   @ 5,787,648   (total 9,787,648 B)
    char* ws = (char*)d_ws;
    float*  rec   = (float*)ws;
    float*  zt    = (float*)(ws + 3145728);
    int*    gcnt  = (int*)(ws + 5705728);
    int*    gbase = (int*)(ws + 5722112);
    int*    gcur  = (int*)(ws + 5738496);
    double* bsum  = (double*)(ws + 5754880);
    int*    pk    = (int*)(ws + 5787648);

    hipMemsetAsync(gcnt, 0, 3 * 16384, stream);         // counts + bases + cursors
    init3<<<NBT + NBH + COLN, 256, 0, stream>>>(
        z_rows, z_cols, gamma_cols, L, col_times, col_idx_list, rec, zt,
        mat_cols, gcnt);
    scatter3<<<NBS, 512, 0, stream>>>(mat_rows, mat_cols, y, gcnt, gcur, gbase, pk);
    edge4<<<COLN, 128, 0, stream>>>(zt, gamma_rows, (const float4*)rec,
                                    b, sigma, pk, gbase, gcnt, bsum);
    finalize2<<<1, 512, 0, stream>>>(bsum, (float*)d_out);
}